// Round 6
// baseline (1440.259 us; speedup 1.0000x reference)
//
#include <hip/hip_runtime.h>
#include <hip/hip_bf16.h>

#define NNODES 50000
#define NREL   16
#define NEDGE  400000
#define BN_EPS 1e-5f
#define M_REAL NNODES
#define MT64   782             /* ceil(50000/64) */
#define SCAN_B 512
#define SCAN_NB ((NNODES + SCAN_B - 1) / SCAN_B)   /* 98 */

typedef __attribute__((ext_vector_type(8))) short short8;
typedef __attribute__((ext_vector_type(4))) float f4;

__device__ __forceinline__ float bf2f(unsigned short u) {
    union { unsigned int i; float f; } x; x.i = ((unsigned int)u) << 16; return x.f;
}
__device__ __forceinline__ unsigned short f2bf(float f) {
    __hip_bfloat16 h = __float2bfloat16(f);
    union { __hip_bfloat16 h; unsigned short u; } x; x.h = h; return x.u;
}

__device__ __forceinline__ void g2l16(const unsigned short* g, unsigned short* l) {
    __builtin_amdgcn_global_load_lds(
        (const __attribute__((address_space(1))) unsigned int*)g,
        (__attribute__((address_space(3))) unsigned int*)l,
        16, 0, 0);
}

// ---------------------------------------------------------------------------
// A-resident merged GEMM: [h | yroot] = A[M,K] @ WT[768,K]^T  (+biasM)
// M-block 64. A staged ONCE (KCH chunks of [64 rows x 64 k], R5 swizzle).
// Then nt=0..5, BK=64, DOUBLE-buffered B (L2-hot weights) -> the per-iter
// barrier drain waits only on B loads issued one compute-phase earlier.
// cols<512 -> h bf16 (stride 512); cols>=512 -> yroot f32 (stride 256).
// ---------------------------------------------------------------------------
template<int K>
__global__ __launch_bounds__(256) void gemm2_k(
    const unsigned short* __restrict__ A,
    const unsigned short* __restrict__ WT,
    const float* __restrict__ biasM,
    unsigned short* __restrict__ h,
    float* __restrict__ yroot)
{
    constexpr int KCH = K / 64;
    __shared__ unsigned short As[KCH * 64 * 64];
    __shared__ unsigned short Bs[2][128 * 64];

    const int tile_m = blockIdx.x * 64;
    const int w = threadIdx.x >> 6;
    const int l = threadIdx.x & 63;
    const int lm = l & 15;
    const int kq = l >> 4;
    const int wm = (w & 1) << 5;     // 0/32
    const int wn = (w >> 1) << 6;    // 0/64
    const int lrow = l >> 3;
    const int lsub = l & 7;
    const int logical = (lsub + 8 - lrow) & 7;   // rows assigned base+lrow -> row&7==lrow

    // ---- A prologue: stage all KCH chunks (wave w covers rows w*16..w*16+15) ----
#pragma unroll
    for (int ch = 0; ch < KCH; ++ch) {
#pragma unroll
        for (int i = 0; i < 2; ++i) {
            int row = w * 16 + i * 8 + lrow;
            int g = tile_m + row; if (g >= M_REAL) g = M_REAL - 1;
            g2l16(A + (size_t)g * K + ch * 64 + logical * 8,
                  As + (ch * 64 + w * 16 + i * 8) * 64);
        }
    }
    // ---- first B chunk ----
    {
        const int nt = 0, kc = 0;
#pragma unroll
        for (int i = 0; i < 4; ++i) {
            int cr = w * 32 + i * 8 + lrow;
            g2l16(WT + (size_t)(nt * 128 + cr) * K + kc * 64 + logical * 8,
                  Bs[0] + (w * 32 + i * 8) * 64);
        }
    }

    int it = 0;
    for (int nt = 0; nt < 6; ++nt) {
        f4 acc[2][4];
#pragma unroll
        for (int mi = 0; mi < 2; ++mi)
#pragma unroll
            for (int ni = 0; ni < 4; ++ni) acc[mi][ni] = (f4){0.f, 0.f, 0.f, 0.f};

        for (int kc = 0; kc < KCH; ++kc) {
            __syncthreads();                 // drains A (first) / prev-issued B
            if (it + 1 < 6 * KCH) {          // prefetch next B into other buffer
                int nit = it + 1;
                int nnt = nit / KCH, nkc = nit % KCH;
#pragma unroll
                for (int i = 0; i < 4; ++i) {
                    int cr = w * 32 + i * 8 + lrow;
                    g2l16(WT + (size_t)(nnt * 128 + cr) * K + nkc * 64 + logical * 8,
                          Bs[(nit) & 1] + (w * 32 + i * 8) * 64);
                }
            }
            const unsigned short* bbase = Bs[it & 1];
#pragma unroll
            for (int kh = 0; kh < 2; ++kh) {
                short8 af[2], bfr[4];
#pragma unroll
                for (int mi = 0; mi < 2; ++mi) {
                    int row = wm + mi * 16 + lm;
                    unsigned off = (unsigned)((kc * 64 + row) * 128 +
                                   (((kh * 4 + kq) + row) & 7) * 16);
                    af[mi] = *(const short8*)((const char*)As + off);
                }
#pragma unroll
                for (int ni = 0; ni < 4; ++ni) {
                    int cr = wn + ni * 16 + lm;
                    unsigned off = (unsigned)(cr * 128 + (((kh * 4 + kq) + cr) & 7) * 16);
                    bfr[ni] = *(const short8*)((const char*)bbase + off);
                }
#pragma unroll
                for (int mi = 0; mi < 2; ++mi)
#pragma unroll
                    for (int ni = 0; ni < 4; ++ni)
                        acc[mi][ni] = __builtin_amdgcn_mfma_f32_16x16x32_bf16(
                            af[mi], bfr[ni], acc[mi][ni], 0, 0, 0);
            }
            ++it;
        }

        // ---- epilogue for this nt ----
        int cols[4]; float bv[4];
#pragma unroll
        for (int ni = 0; ni < 4; ++ni) {
            cols[ni] = nt * 128 + wn + ni * 16 + lm;
            bv[ni] = biasM[cols[ni]];
        }
#pragma unroll
        for (int mi = 0; mi < 2; ++mi) {
#pragma unroll
            for (int rg = 0; rg < 4; ++rg) {
                int row = tile_m + wm + mi * 16 + kq * 4 + rg;
                if (row < M_REAL) {
                    if (nt < 4) {
                        size_t base = (size_t)row * 512;
#pragma unroll
                        for (int ni = 0; ni < 4; ++ni)
                            h[base + cols[ni]] = f2bf(acc[mi][ni][rg] + bv[ni]);
                    } else {
                        size_t base = (size_t)row * 256;
#pragma unroll
                        for (int ni = 0; ni < 4; ++ni)
                            yroot[base + cols[ni] - 512] = acc[mi][ni][rg] + bv[ni];
                    }
                }
            }
        }
    }
}

// row L2-normalize emb -> bf16 x0 [50000 x 128]
__global__ __launch_bounds__(256) void norm_k(const float* __restrict__ emb,
                                              unsigned short* __restrict__ x0)
{
    int node = blockIdx.x * 4 + (threadIdx.x >> 6);
    int lane = threadIdx.x & 63;
    const float2* p = (const float2*)(emb + (size_t)node * 128);
    float2 v = p[lane];
    float ss = v.x * v.x + v.y * v.y;
#pragma unroll
    for (int o = 32; o > 0; o >>= 1) ss += __shfl_xor(ss, o);
    float inv = 1.f / fmaxf(sqrtf(ss), 1e-12f);
    unsigned int pack = (unsigned int)f2bf(v.x * inv) | ((unsigned int)f2bf(v.y * inv) << 16);
    ((unsigned int*)(x0 + (size_t)node * 128))[lane] = pack;
}

// zero cnt(800000) cntd(50000) cursor(50000) bns(1536)
__global__ void zero_k(unsigned int* __restrict__ cnt, unsigned int* __restrict__ cntd,
                       unsigned int* __restrict__ cursor, float* __restrict__ bns)
{
    int i = blockIdx.x * 256 + threadIdx.x;
    if (i < 800000) cnt[i] = 0u;
    if (i < 50000) { cntd[i] = 0u; cursor[i] = 0u; }
    if (i < 1536) bns[i] = 0.f;
}

__global__ void cnt_k(const int* __restrict__ ei, const int* __restrict__ et,
                      unsigned int* __restrict__ cnt, unsigned int* __restrict__ cntd)
{
    int e = blockIdx.x * 256 + threadIdx.x;
    if (e >= NEDGE) return;
    int dst = ei[NEDGE + e];
    atomicAdd(&cnt[(size_t)dst * NREL + et[e]], 1u);
    atomicAdd(&cntd[dst], 1u);
}

__global__ __launch_bounds__(SCAN_B) void scan1_k(const unsigned int* __restrict__ cntd,
                                                  unsigned int* __restrict__ partial,
                                                  unsigned int* __restrict__ bsum)
{
    __shared__ unsigned int s[SCAN_B];
    int i = blockIdx.x * SCAN_B + threadIdx.x;
    unsigned int v = (i < NNODES) ? cntd[i] : 0u;
    s[threadIdx.x] = v;
    __syncthreads();
    for (int off = 1; off < SCAN_B; off <<= 1) {
        unsigned int t = (threadIdx.x >= off) ? s[threadIdx.x - off] : 0u;
        __syncthreads();
        s[threadIdx.x] += t;
        __syncthreads();
    }
    if (i < NNODES) partial[i] = s[threadIdx.x];
    if (threadIdx.x == SCAN_B - 1) bsum[blockIdx.x] = s[SCAN_B - 1];
}

__global__ __launch_bounds__(128) void scan2_k(unsigned int* __restrict__ bsum)
{
    __shared__ unsigned int s[128];
    unsigned int v = (threadIdx.x < SCAN_NB) ? bsum[threadIdx.x] : 0u;
    s[threadIdx.x] = v;
    __syncthreads();
    for (int off = 1; off < 128; off <<= 1) {
        unsigned int t = (threadIdx.x >= off) ? s[threadIdx.x - off] : 0u;
        __syncthreads();
        s[threadIdx.x] += t;
        __syncthreads();
    }
    if (threadIdx.x < SCAN_NB) bsum[threadIdx.x] = s[threadIdx.x];
}

__global__ __launch_bounds__(SCAN_B) void scan3_k(const unsigned int* __restrict__ partial,
                                                  const unsigned int* __restrict__ bsum,
                                                  unsigned int* __restrict__ rowptr)
{
    int i = blockIdx.x * SCAN_B + threadIdx.x;
    if (i >= NNODES) return;
    unsigned int off = (blockIdx.x > 0) ? bsum[blockIdx.x - 1] : 0u;
    rowptr[i + 1] = partial[i] + off;
    if (i == 0) rowptr[0] = 0u;
}

__global__ void fill_k(const int* __restrict__ ei, const int* __restrict__ et,
                       const unsigned int* __restrict__ cnt,
                       const unsigned int* __restrict__ rowptr,
                       unsigned int* __restrict__ cursor,
                       float2* __restrict__ erec)
{
    int e = blockIdx.x * 256 + threadIdx.x;
    if (e >= NEDGE) return;
    int dst = ei[NEDGE + e];
    int t = et[e];
    unsigned int c = cnt[(size_t)dst * NREL + t];
    unsigned int pos = rowptr[dst] + atomicAdd(&cursor[dst], 1u);
    float2 r;
    r.x = __uint_as_float(((unsigned)ei[e] << 4) | (unsigned)t);
    r.y = 1.f / (float)(c ? c : 1u);
    erec[pos] = r;
}

// gather + root-add + BN-sum: 3125 blocks, wave handles 4 nodes
__global__ __launch_bounds__(256) void gather2_k(
    const unsigned short* __restrict__ h, const float* __restrict__ comp,
    const unsigned int* __restrict__ rowptr, const float2* __restrict__ erec,
    const float* __restrict__ yroot, float* __restrict__ y,
    float* __restrict__ bns)
{
    __shared__ float scomp[32];
    __shared__ f4 sred[512];
    if (threadIdx.x < 32) scomp[threadIdx.x] = comp[threadIdx.x];
    __syncthreads();
    int w = threadIdx.x >> 6;
    int lane = threadIdx.x & 63;
    f4 s1 = (f4){0.f,0.f,0.f,0.f}, s2 = (f4){0.f,0.f,0.f,0.f};
#pragma unroll
    for (int i = 0; i < 4; ++i) {
        int node = blockIdx.x * 16 + w * 4 + i;
        unsigned int p0 = rowptr[node], p1 = rowptr[node + 1];
        f4 accA = (f4){0.f,0.f,0.f,0.f};
        f4 accB = (f4){0.f,0.f,0.f,0.f};
        unsigned int p = p0;
        for (; p + 2 <= p1; p += 2) {
            float2 r0 = erec[p];
            float2 r1 = erec[p + 1];
            unsigned q0 = __float_as_uint(r0.x);
            unsigned q1 = __float_as_uint(r1.x);
            const unsigned short* hp0 = h + (size_t)(q0 >> 4) * 512 + lane * 4;
            const unsigned short* hp1 = h + (size_t)(q1 >> 4) * 512 + lane * 4;
            ushort4 a0 = *(const ushort4*)hp0;
            ushort4 b0 = *(const ushort4*)(hp0 + 256);
            ushort4 a1 = *(const ushort4*)hp1;
            ushort4 b1 = *(const ushort4*)(hp1 + 256);
            float w00 = scomp[(q0 & 15) * 2] * r0.y, w01 = scomp[(q0 & 15) * 2 + 1] * r0.y;
            float w10 = scomp[(q1 & 15) * 2] * r1.y, w11 = scomp[(q1 & 15) * 2 + 1] * r1.y;
            accA.x += w00 * bf2f(a0.x) + w01 * bf2f(b0.x);
            accA.y += w00 * bf2f(a0.y) + w01 * bf2f(b0.y);
            accA.z += w00 * bf2f(a0.z) + w01 * bf2f(b0.z);
            accA.w += w00 * bf2f(a0.w) + w01 * bf2f(b0.w);
            accB.x += w10 * bf2f(a1.x) + w11 * bf2f(b1.x);
            accB.y += w10 * bf2f(a1.y) + w11 * bf2f(b1.y);
            accB.z += w10 * bf2f(a1.z) + w11 * bf2f(b1.z);
            accB.w += w10 * bf2f(a1.w) + w11 * bf2f(b1.w);
        }
        if (p < p1) {
            float2 r0 = erec[p];
            unsigned q0 = __float_as_uint(r0.x);
            const unsigned short* hp0 = h + (size_t)(q0 >> 4) * 512 + lane * 4;
            ushort4 a0 = *(const ushort4*)hp0;
            ushort4 b0 = *(const ushort4*)(hp0 + 256);
            float w00 = scomp[(q0 & 15) * 2] * r0.y, w01 = scomp[(q0 & 15) * 2 + 1] * r0.y;
            accA.x += w00 * bf2f(a0.x) + w01 * bf2f(b0.x);
            accA.y += w00 * bf2f(a0.y) + w01 * bf2f(b0.y);
            accA.z += w00 * bf2f(a0.z) + w01 * bf2f(b0.z);
            accA.w += w00 * bf2f(a0.w) + w01 * bf2f(b0.w);
        }
        f4 yr = *(const f4*)(yroot + (size_t)node * 256 + lane * 4);
        f4 v;
        v.x = accA.x + accB.x + yr.x;
        v.y = accA.y + accB.y + yr.y;
        v.z = accA.z + accB.z + yr.z;
        v.w = accA.w + accB.w + yr.w;
        *(f4*)(y + (size_t)node * 256 + lane * 4) = v;
        s1.x += v.x; s1.y += v.y; s1.z += v.z; s1.w += v.w;
        s2.x += v.x*v.x; s2.y += v.y*v.y; s2.z += v.z*v.z; s2.w += v.w*v.w;
    }
    sred[(w * 64 + lane) * 2] = s1;
    sred[(w * 64 + lane) * 2 + 1] = s2;
    __syncthreads();
    if (w == 0) {
        f4 t1 = (f4){0.f,0.f,0.f,0.f}, t2 = (f4){0.f,0.f,0.f,0.f};
#pragma unroll
        for (int ww = 0; ww < 4; ++ww) {
            f4 a = sred[(ww * 64 + lane) * 2];
            f4 b = sred[(ww * 64 + lane) * 2 + 1];
            t1.x += a.x; t1.y += a.y; t1.z += a.z; t1.w += a.w;
            t2.x += b.x; t2.y += b.y; t2.z += b.z; t2.w += b.w;
        }
        int c = lane * 4;
        atomicAdd(&bns[c + 0], t1.x); atomicAdd(&bns[c + 1], t1.y);
        atomicAdd(&bns[c + 2], t1.z); atomicAdd(&bns[c + 3], t1.w);
        atomicAdd(&bns[256 + c + 0], t2.x); atomicAdd(&bns[256 + c + 1], t2.y);
        atomicAdd(&bns[256 + c + 2], t2.z); atomicAdd(&bns[256 + c + 3], t2.w);
    }
}

// PT[j*128+d] = proj_w[d*768+j]  (f32 transpose)
__global__ __launch_bounds__(128) void pt_k(const float* __restrict__ proj_w,
                                            float* __restrict__ PT)
{
    int j = blockIdx.x, d = threadIdx.x;
    PT[(size_t)j * 128 + d] = proj_w[(size_t)d * 768 + j];
}

// wTm0[n*128+d] = sum_j PT[j*128+d] * W0[j][n];  biasM0[n] = pb@W0[:,n] (+root bias)
__global__ __launch_bounds__(128) void pm_k(
    const float* __restrict__ PT, const float* __restrict__ pb,
    const float* __restrict__ b0, const float* __restrict__ r0,
    const float* __restrict__ bias0,
    unsigned short* __restrict__ wTm0, float* __restrict__ biasM0)
{
    __shared__ float sw[128];
    __shared__ float spb[128];
    __shared__ float red[2];
    int n = blockIdx.x, d = threadIdx.x;
    float acc = 0.f, accb = 0.f;
    for (int ch = 0; ch < 6; ++ch) {
        int j0 = ch * 128;
        __syncthreads();
        int j = j0 + d;
        float wv;
        if (n < 256)      wv = b0[(size_t)j * 256 + n];
        else if (n < 512) wv = b0[768 * 256 + (size_t)j * 256 + (n - 256)];
        else              wv = r0[(size_t)j * 256 + (n - 512)];
        sw[d] = wv;
        spb[d] = pb[j];
        __syncthreads();
#pragma unroll 8
        for (int jj = 0; jj < 128; ++jj)
            acc += PT[(size_t)(j0 + jj) * 128 + d] * sw[jj];
        accb += spb[d] * sw[d];
    }
    // reduce accb over 128 threads (2 waves)
    for (int o = 32; o > 0; o >>= 1) accb += __shfl_xor(accb, o);
    if ((d & 63) == 0) red[d >> 6] = accb;
    __syncthreads();
    if (d == 0)
        biasM0[n] = red[0] + red[1] + (n >= 512 ? bias0[n - 512] : 0.f);
    wTm0[(size_t)n * 128 + d] = f2bf(acc);
}

// l1/l2 weight transposes (f32 [768x256] -> bf16 [768xK=256]) + biasM fills
// blocks 0..767: layer1 (seg=b/256? no: 3 segs x 256 k) ; 768..1535: layer2 ; 1536..1541 bias
__global__ __launch_bounds__(256) void prep_k(
    const float* __restrict__ b1, const float* __restrict__ r1, const float* __restrict__ bias1,
    const float* __restrict__ b2, const float* __restrict__ r2, const float* __restrict__ bias2,
    unsigned short* __restrict__ wTm1, unsigned short* __restrict__ wTm2,
    float* __restrict__ biasM1, float* __restrict__ biasM2)
{
    int b = blockIdx.x;
    if (b < 1536) {
        int layer = b / 768;
        int r = b % 768;
        int seg = r / 256;
        int k = r % 256;
        const float* bb = layer ? b2 : b1;
        const float* rr = layer ? r2 : r1;
        const float* in = (seg < 2) ? (bb + (size_t)seg * 256 * 256) : rr;
        unsigned short* out = layer ? wTm2 : wTm1;
        out[(size_t)(seg * 256 + threadIdx.x) * 256 + k] = f2bf(in[(size_t)k * 256 + threadIdx.x]);
    } else {
        int i = b - 1536;          // 0..5
        int layer = i / 3;
        int part = i % 3;
        int n = part * 256 + threadIdx.x;
        float* bm = layer ? biasM2 : biasM1;
        const float* bs = layer ? bias2 : bias1;
        bm[n] = (n >= 512) ? bs[n - 512] : 0.f;
    }
}

__global__ void bnfin_k(const float* __restrict__ bnsum, const float* __restrict__ gamma,
                        const float* __restrict__ beta, float* __restrict__ bnss)
{
    int c = threadIdx.x;
    float mu = bnsum[c] * (1.f / M_REAL);
    float var = bnsum[256 + c] * (1.f / M_REAL) - mu * mu;
    var = fmaxf(var, 0.f);
    float inv = rsqrtf(var + BN_EPS);
    float sc = gamma[c] * inv;
    bnss[c] = sc;
    bnss[256 + c] = beta[c] - mu * sc;
}

template<bool LAST>
__global__ __launch_bounds__(256) void apply_k(const float* __restrict__ y,
                                               const float* __restrict__ bnss,
                                               unsigned short* __restrict__ xn,
                                               float* __restrict__ outp)
{
    int i = blockIdx.x * 256 + threadIdx.x;
    int row = i >> 6;
    int c4 = (i & 63) * 4;
    f4 v = *(const f4*)(y + (size_t)row * 256 + c4);
    f4 sc = *(const f4*)(bnss + c4);
    f4 sh = *(const f4*)(bnss + 256 + c4);
    f4 r;
    r.x = fmaxf(v.x * sc.x + sh.x, 0.f);
    r.y = fmaxf(v.y * sc.y + sh.y, 0.f);
    r.z = fmaxf(v.z * sc.z + sh.z, 0.f);
    r.w = fmaxf(v.w * sc.w + sh.w, 0.f);
    if (LAST) {
        *(f4*)(outp + (size_t)row * 256 + c4) = r;
    } else {
        ushort4 u;
        u.x = f2bf(r.x); u.y = f2bf(r.y); u.z = f2bf(r.z); u.w = f2bf(r.w);
        *(ushort4*)(xn + (size_t)row * 256 + c4) = u;
    }
}

extern "C" void kernel_launch(void* const* d_in, const int* in_sizes, int n_in,
                              void* d_out, int out_size, void* d_ws, size_t ws_size,
                              hipStream_t stream)
{
    const int*   edge_index = (const int*)d_in[0];
    const int*   edge_type  = (const int*)d_in[1];
    const float* emb    = (const float*)d_in[2];
    const float* proj_w = (const float*)d_in[3];
    const float* proj_b = (const float*)d_in[4];
    const float* comp[3]  = {(const float*)d_in[5],  (const float*)d_in[11], (const float*)d_in[17]};
    const float* bases[3] = {(const float*)d_in[6],  (const float*)d_in[12], (const float*)d_in[18]};
    const float* root[3]  = {(const float*)d_in[7],  (const float*)d_in[13], (const float*)d_in[19]};
    const float* biasp[3] = {(const float*)d_in[8],  (const float*)d_in[14], (const float*)d_in[20]};
    const float* gamma[3] = {(const float*)d_in[9],  (const float*)d_in[15], (const float*)d_in[21]};
    const float* beta[3]  = {(const float*)d_in[10], (const float*)d_in[16], (const float*)d_in[22]};

    char* ws = (char*)d_ws;
    size_t off = 0;
    auto alloc = [&](size_t bytes) -> char* {
        char* p = ws + off;
        off = (off + bytes + 255) & ~(size_t)255;
        return p;
    };

    float*          y    = (float*)alloc((size_t)NNODES * 256 * 4);   // x0 aliased at start
    unsigned short* x1   = (unsigned short*)alloc((size_t)NNODES * 256 * 2);
    unsigned short* x2   = (unsigned short*)alloc((size_t)NNODES * 256 * 2);
    unsigned short* h    = (unsigned short*)alloc((size_t)NNODES * 512 * 2);
    float*          yroot= (float*)alloc((size_t)NNODES * 256 * 4);
    unsigned int*   cnt  = (unsigned int*)alloc((size_t)NNODES * NREL * 4);
    unsigned int*   cntd = (unsigned int*)alloc((size_t)NNODES * 4);
    unsigned int*   rowptr = (unsigned int*)alloc((size_t)(NNODES + 1) * 4);
    unsigned int*   cursor = (unsigned int*)alloc((size_t)NNODES * 4);
    unsigned int*   partial = (unsigned int*)alloc((size_t)NNODES * 4);
    unsigned int*   bsum = (unsigned int*)alloc(128 * 4);
    float2*         erec = (float2*)alloc((size_t)NEDGE * 8);
    float*          PT   = (float*)alloc((size_t)768 * 128 * 4);
    unsigned short* wTm0 = (unsigned short*)alloc((size_t)768 * 128 * 2);
    unsigned short* wTm1 = (unsigned short*)alloc((size_t)768 * 256 * 2);
    unsigned short* wTm2 = (unsigned short*)alloc((size_t)768 * 256 * 2);
    float* biasM = (float*)alloc(3 * 768 * 4);
    float* bns   = (float*)alloc(3 * 512 * 4);
    float* bnss  = (float*)alloc(3 * 512 * 4);

    unsigned short* x0 = (unsigned short*)y;   // x0 dead before y first written (gather l0)

    zero_k<<<3125, 256, 0, stream>>>(cnt, cntd, cursor, bns);
    norm_k<<<NNODES / 4, 256, 0, stream>>>(emb, x0);
    cnt_k<<<(NEDGE + 255) / 256, 256, 0, stream>>>(edge_index, edge_type, cnt, cntd);
    scan1_k<<<SCAN_NB, SCAN_B, 0, stream>>>(cntd, partial, bsum);
    scan2_k<<<1, 128, 0, stream>>>(bsum);
    scan3_k<<<SCAN_NB, SCAN_B, 0, stream>>>(partial, bsum, rowptr);
    fill_k<<<(NEDGE + 255) / 256, 256, 0, stream>>>(edge_index, edge_type, cnt, rowptr,
                                                    cursor, erec);

    pt_k<<<768, 128, 0, stream>>>(proj_w, PT);
    pm_k<<<768, 128, 0, stream>>>(PT, proj_b, bases[0], root[0], biasp[0], wTm0, biasM);
    prep_k<<<1542, 256, 0, stream>>>(bases[1], root[1], biasp[1],
                                     bases[2], root[2], biasp[2],
                                     wTm1, wTm2, biasM + 768, biasM + 2 * 768);

    // ---- layer 0 (A = x0, K = 128 after P-folding) ----
    gemm2_k<128><<<MT64, 256, 0, stream>>>(x0, wTm0, biasM, h, yroot);
    gather2_k<<<NNODES / 16, 256, 0, stream>>>(h, comp[0], rowptr, erec, yroot, y, bns);
    bnfin_k<<<1, 256, 0, stream>>>(bns, gamma[0], beta[0], bnss);
    apply_k<false><<<(NNODES * 64) / 256, 256, 0, stream>>>(y, bnss, x1, nullptr);

    // ---- layer 1 (K = 256) ----
    gemm2_k<256><<<MT64, 256, 0, stream>>>(x1, wTm1, biasM + 768, h, yroot);
    gather2_k<<<NNODES / 16, 256, 0, stream>>>(h, comp[1], rowptr, erec, yroot, y, bns + 512);
    bnfin_k<<<1, 256, 0, stream>>>(bns + 512, gamma[1], beta[1], bnss + 512);
    apply_k<false><<<(NNODES * 64) / 256, 256, 0, stream>>>(y, bnss + 512, x2, nullptr);

    // ---- layer 2 (K = 256) ----
    gemm2_k<256><<<MT64, 256, 0, stream>>>(x2, wTm2, biasM + 2 * 768, h, yroot);
    gather2_k<<<NNODES / 16, 256, 0, stream>>>(h, comp[2], rowptr, erec, yroot, y, bns + 1024);
    bnfin_k<<<1, 256, 0, stream>>>(bns + 1024, gamma[2], beta[2], bnss + 1024);
    apply_k<true><<<(NNODES * 64) / 256, 256, 0, stream>>>(y, bnss + 1024, nullptr, (float*)d_out);
}

// Round 7
// 693.558 us; speedup vs baseline: 2.0766x; 2.0766x over previous
//
#include <hip/hip_runtime.h>
#include <hip/hip_bf16.h>

#define NNODES 50000
#define NREL   16
#define NEDGE  400000
#define BN_EPS 1e-5f
#define M_REAL NNODES
#define MT64   782             /* ceil(50000/64) */
#define SCAN_B 512
#define SCAN_NB ((NNODES + SCAN_B - 1) / SCAN_B)   /* 98 */

typedef __attribute__((ext_vector_type(8))) short short8;
typedef __attribute__((ext_vector_type(4))) float f4;

__device__ __forceinline__ float bf2f(unsigned short u) {
    union { unsigned int i; float f; } x; x.i = ((unsigned int)u) << 16; return x.f;
}
__device__ __forceinline__ unsigned short f2bf(float f) {
    __hip_bfloat16 h = __float2bfloat16(f);
    union { __hip_bfloat16 h; unsigned short u; } x; x.h = h; return x.u;
}

__device__ __forceinline__ void g2l16(const unsigned short* g, unsigned short* l) {
    __builtin_amdgcn_global_load_lds(
        (const __attribute__((address_space(1))) unsigned int*)g,
        (__attribute__((address_space(3))) unsigned int*)l,
        16, 0, 0);
}

// ---------------------------------------------------------------------------
// A-resident merged GEMM: [h | yroot] = A[M,K] @ WT[768,K]^T  (+biasM)
// M-block 64. A staged ONCE; nt=0..5 with double-buffered L2-hot B chunks.
// ---------------------------------------------------------------------------
template<int K>
__global__ __launch_bounds__(256) void gemm2_k(
    const unsigned short* __restrict__ A,
    const unsigned short* __restrict__ WT,
    const float* __restrict__ biasM,
    unsigned short* __restrict__ h,
    float* __restrict__ yroot)
{
    constexpr int KCH = K / 64;
    __shared__ unsigned short As[KCH * 64 * 64];
    __shared__ unsigned short Bs[2][128 * 64];

    const int tile_m = blockIdx.x * 64;
    const int w = threadIdx.x >> 6;
    const int l = threadIdx.x & 63;
    const int lm = l & 15;
    const int kq = l >> 4;
    const int wm = (w & 1) << 5;     // 0/32
    const int wn = (w >> 1) << 6;    // 0/64
    const int lrow = l >> 3;
    const int lsub = l & 7;
    const int logical = (lsub + 8 - lrow) & 7;

    // ---- A prologue: stage all KCH chunks ----
#pragma unroll
    for (int ch = 0; ch < KCH; ++ch) {
#pragma unroll
        for (int i = 0; i < 2; ++i) {
            int row = w * 16 + i * 8 + lrow;
            int g = tile_m + row; if (g >= M_REAL) g = M_REAL - 1;
            g2l16(A + (size_t)g * K + ch * 64 + logical * 8,
                  As + (ch * 64 + w * 16 + i * 8) * 64);
        }
    }
    // ---- first B chunk ----
    {
#pragma unroll
        for (int i = 0; i < 4; ++i) {
            int cr = w * 32 + i * 8 + lrow;
            g2l16(WT + (size_t)cr * K + logical * 8,
                  Bs[0] + (w * 32 + i * 8) * 64);
        }
    }

    int it = 0;
    for (int nt = 0; nt < 6; ++nt) {
        f4 acc[2][4];
#pragma unroll
        for (int mi = 0; mi < 2; ++mi)
#pragma unroll
            for (int ni = 0; ni < 4; ++ni) acc[mi][ni] = (f4){0.f, 0.f, 0.f, 0.f};

        for (int kc = 0; kc < KCH; ++kc) {
            __syncthreads();
            if (it + 1 < 6 * KCH) {
                int nit = it + 1;
                int nnt = nit / KCH, nkc = nit % KCH;
#pragma unroll
                for (int i = 0; i < 4; ++i) {
                    int cr = w * 32 + i * 8 + lrow;
                    g2l16(WT + (size_t)(nnt * 128 + cr) * K + nkc * 64 + logical * 8,
                          Bs[nit & 1] + (w * 32 + i * 8) * 64);
                }
            }
            const unsigned short* bbase = Bs[it & 1];
#pragma unroll
            for (int kh = 0; kh < 2; ++kh) {
                short8 af[2], bfr[4];
#pragma unroll
                for (int mi = 0; mi < 2; ++mi) {
                    int row = wm + mi * 16 + lm;
                    unsigned off = (unsigned)((kc * 64 + row) * 128 +
                                   (((kh * 4 + kq) + row) & 7) * 16);
                    af[mi] = *(const short8*)((const char*)As + off);
                }
#pragma unroll
                for (int ni = 0; ni < 4; ++ni) {
                    int cr = wn + ni * 16 + lm;
                    unsigned off = (unsigned)(cr * 128 + (((kh * 4 + kq) + cr) & 7) * 16);
                    bfr[ni] = *(const short8*)((const char*)bbase + off);
                }
#pragma unroll
                for (int mi = 0; mi < 2; ++mi)
#pragma unroll
                    for (int ni = 0; ni < 4; ++ni)
                        acc[mi][ni] = __builtin_amdgcn_mfma_f32_16x16x32_bf16(
                            af[mi], bfr[ni], acc[mi][ni], 0, 0, 0);
            }
            ++it;
        }

        int cols[4]; float bv[4];
#pragma unroll
        for (int ni = 0; ni < 4; ++ni) {
            cols[ni] = nt * 128 + wn + ni * 16 + lm;
            bv[ni] = biasM[cols[ni]];
        }
#pragma unroll
        for (int mi = 0; mi < 2; ++mi) {
#pragma unroll
            for (int rg = 0; rg < 4; ++rg) {
                int row = tile_m + wm + mi * 16 + kq * 4 + rg;
                if (row < M_REAL) {
                    if (nt < 4) {
                        size_t base = (size_t)row * 512;
#pragma unroll
                        for (int ni = 0; ni < 4; ++ni)
                            h[base + cols[ni]] = f2bf(acc[mi][ni][rg] + bv[ni]);
                    } else {
                        size_t base = (size_t)row * 256;
#pragma unroll
                        for (int ni = 0; ni < 4; ++ni)
                            yroot[base + cols[ni] - 512] = acc[mi][ni][rg] + bv[ni];
                    }
                }
            }
        }
    }
}

// row L2-normalize emb -> bf16 x0 [50000 x 128]
__global__ __launch_bounds__(256) void norm_k(const float* __restrict__ emb,
                                              unsigned short* __restrict__ x0)
{
    int node = blockIdx.x * 4 + (threadIdx.x >> 6);
    int lane = threadIdx.x & 63;
    const float2* p = (const float2*)(emb + (size_t)node * 128);
    float2 v = p[lane];
    float ss = v.x * v.x + v.y * v.y;
#pragma unroll
    for (int o = 32; o > 0; o >>= 1) ss += __shfl_xor(ss, o);
    float inv = 1.f / fmaxf(sqrtf(ss), 1e-12f);
    unsigned int pack = (unsigned int)f2bf(v.x * inv) | ((unsigned int)f2bf(v.y * inv) << 16);
    ((unsigned int*)(x0 + (size_t)node * 128))[lane] = pack;
}

// zero cnt(800000) cntd(50000) cursor(50000) bns(1536)
__global__ void zero_k(unsigned int* __restrict__ cnt, unsigned int* __restrict__ cntd,
                       unsigned int* __restrict__ cursor, float* __restrict__ bns)
{
    int i = blockIdx.x * 256 + threadIdx.x;
    if (i < 800000) cnt[i] = 0u;
    if (i < 50000) { cntd[i] = 0u; cursor[i] = 0u; }
    if (i < 1536) bns[i] = 0.f;
}

__global__ void cnt_k(const int* __restrict__ ei, const int* __restrict__ et,
                      unsigned int* __restrict__ cnt, unsigned int* __restrict__ cntd)
{
    int e = blockIdx.x * 256 + threadIdx.x;
    if (e >= NEDGE) return;
    int dst = ei[NEDGE + e];
    atomicAdd(&cnt[(size_t)dst * NREL + et[e]], 1u);
    atomicAdd(&cntd[dst], 1u);
}

__global__ __launch_bounds__(SCAN_B) void scan1_k(const unsigned int* __restrict__ cntd,
                                                  unsigned int* __restrict__ partial,
                                                  unsigned int* __restrict__ bsum)
{
    __shared__ unsigned int s[SCAN_B];
    int i = blockIdx.x * SCAN_B + threadIdx.x;
    unsigned int v = (i < NNODES) ? cntd[i] : 0u;
    s[threadIdx.x] = v;
    __syncthreads();
    for (int off = 1; off < SCAN_B; off <<= 1) {
        unsigned int t = (threadIdx.x >= off) ? s[threadIdx.x - off] : 0u;
        __syncthreads();
        s[threadIdx.x] += t;
        __syncthreads();
    }
    if (i < NNODES) partial[i] = s[threadIdx.x];
    if (threadIdx.x == SCAN_B - 1) bsum[blockIdx.x] = s[SCAN_B - 1];
}

__global__ __launch_bounds__(128) void scan2_k(unsigned int* __restrict__ bsum)
{
    __shared__ unsigned int s[128];
    unsigned int v = (threadIdx.x < SCAN_NB) ? bsum[threadIdx.x] : 0u;
    s[threadIdx.x] = v;
    __syncthreads();
    for (int off = 1; off < 128; off <<= 1) {
        unsigned int t = (threadIdx.x >= off) ? s[threadIdx.x - off] : 0u;
        __syncthreads();
        s[threadIdx.x] += t;
        __syncthreads();
    }
    if (threadIdx.x < SCAN_NB) bsum[threadIdx.x] = s[threadIdx.x];
}

__global__ __launch_bounds__(SCAN_B) void scan3_k(const unsigned int* __restrict__ partial,
                                                  const unsigned int* __restrict__ bsum,
                                                  unsigned int* __restrict__ rowptr)
{
    int i = blockIdx.x * SCAN_B + threadIdx.x;
    if (i >= NNODES) return;
    unsigned int off = (blockIdx.x > 0) ? bsum[blockIdx.x - 1] : 0u;
    rowptr[i + 1] = partial[i] + off;
    if (i == 0) rowptr[0] = 0u;
}

__global__ void fill_k(const int* __restrict__ ei, const int* __restrict__ et,
                       const unsigned int* __restrict__ cnt,
                       const unsigned int* __restrict__ rowptr,
                       unsigned int* __restrict__ cursor,
                       float2* __restrict__ erec)
{
    int e = blockIdx.x * 256 + threadIdx.x;
    if (e >= NEDGE) return;
    int dst = ei[NEDGE + e];
    int t = et[e];
    unsigned int c = cnt[(size_t)dst * NREL + t];
    unsigned int pos = rowptr[dst] + atomicAdd(&cursor[dst], 1u);
    float2 r;
    r.x = __uint_as_float(((unsigned)ei[e] << 4) | (unsigned)t);
    r.y = 1.f / (float)(c ? c : 1u);
    erec[pos] = r;
}

// one wave per dst node (R5-verified shape) + fused yroot add:
// y[dst] = sum_e w0*h0[src] + w1*h1[src] + yroot[dst]
__global__ __launch_bounds__(256) void gather3_k(
    const unsigned short* __restrict__ h, const float* __restrict__ comp,
    const unsigned int* __restrict__ rowptr, const float2* __restrict__ erec,
    const float* __restrict__ yroot, float* __restrict__ y)
{
    __shared__ float scomp[32];
    if (threadIdx.x < 32) scomp[threadIdx.x] = comp[threadIdx.x];
    __syncthreads();
    int node = blockIdx.x * 4 + (threadIdx.x >> 6);
    int lane = threadIdx.x & 63;
    unsigned int p0 = rowptr[node], p1 = rowptr[node + 1];
    f4 accA = (f4){0.f, 0.f, 0.f, 0.f};
    f4 accB = (f4){0.f, 0.f, 0.f, 0.f};
    unsigned int p = p0;
    for (; p + 2 <= p1; p += 2) {
        float2 r0 = erec[p];
        float2 r1 = erec[p + 1];
        unsigned q0 = __float_as_uint(r0.x);
        unsigned q1 = __float_as_uint(r1.x);
        const unsigned short* hp0 = h + (size_t)(q0 >> 4) * 512 + lane * 4;
        const unsigned short* hp1 = h + (size_t)(q1 >> 4) * 512 + lane * 4;
        ushort4 a0 = *(const ushort4*)hp0;
        ushort4 b0 = *(const ushort4*)(hp0 + 256);
        ushort4 a1 = *(const ushort4*)hp1;
        ushort4 b1 = *(const ushort4*)(hp1 + 256);
        float w00 = scomp[(q0 & 15) * 2] * r0.y, w01 = scomp[(q0 & 15) * 2 + 1] * r0.y;
        float w10 = scomp[(q1 & 15) * 2] * r1.y, w11 = scomp[(q1 & 15) * 2 + 1] * r1.y;
        accA.x += w00 * bf2f(a0.x) + w01 * bf2f(b0.x);
        accA.y += w00 * bf2f(a0.y) + w01 * bf2f(b0.y);
        accA.z += w00 * bf2f(a0.z) + w01 * bf2f(b0.z);
        accA.w += w00 * bf2f(a0.w) + w01 * bf2f(b0.w);
        accB.x += w10 * bf2f(a1.x) + w11 * bf2f(b1.x);
        accB.y += w10 * bf2f(a1.y) + w11 * bf2f(b1.y);
        accB.z += w10 * bf2f(a1.z) + w11 * bf2f(b1.z);
        accB.w += w10 * bf2f(a1.w) + w11 * bf2f(b1.w);
    }
    if (p < p1) {
        float2 r0 = erec[p];
        unsigned q0 = __float_as_uint(r0.x);
        const unsigned short* hp0 = h + (size_t)(q0 >> 4) * 512 + lane * 4;
        ushort4 a0 = *(const ushort4*)hp0;
        ushort4 b0 = *(const ushort4*)(hp0 + 256);
        float w00 = scomp[(q0 & 15) * 2] * r0.y, w01 = scomp[(q0 & 15) * 2 + 1] * r0.y;
        accA.x += w00 * bf2f(a0.x) + w01 * bf2f(b0.x);
        accA.y += w00 * bf2f(a0.y) + w01 * bf2f(b0.y);
        accA.z += w00 * bf2f(a0.z) + w01 * bf2f(b0.z);
        accA.w += w00 * bf2f(a0.w) + w01 * bf2f(b0.w);
    }
    f4 yr = *(const f4*)(yroot + (size_t)node * 256 + lane * 4);
    f4 v;
    v.x = accA.x + accB.x + yr.x;
    v.y = accA.y + accB.y + yr.y;
    v.z = accA.z + accB.z + yr.z;
    v.w = accA.w + accB.w + yr.w;
    *(f4*)(y + (size_t)node * 256 + lane * 4) = v;
}

// BN sums over y: 500 blocks x 100 rows; thread owns one column; 2 atomics/thread
__global__ __launch_bounds__(256) void bnsum_k(const float* __restrict__ y,
                                               float* __restrict__ bns)
{
    int c = threadIdx.x;
    int r0 = blockIdx.x * 100;
    float s1 = 0.f, s2 = 0.f;
    for (int r = r0; r < r0 + 100; ++r) {
        float v = y[(size_t)r * 256 + c];
        s1 += v; s2 += v * v;
    }
    atomicAdd(&bns[c], s1);
    atomicAdd(&bns[256 + c], s2);
}

// PT[j*128+d] = proj_w[d*768+j]  (f32 transpose)
__global__ __launch_bounds__(128) void pt_k(const float* __restrict__ proj_w,
                                            float* __restrict__ PT)
{
    int j = blockIdx.x, d = threadIdx.x;
    PT[(size_t)j * 128 + d] = proj_w[(size_t)d * 768 + j];
}

// wTm0[n*128+d] = sum_j PT[j*128+d] * W0[j][n];  biasM0[n] = pb@W0[:,n] (+root bias)
__global__ __launch_bounds__(128) void pm_k(
    const float* __restrict__ PT, const float* __restrict__ pb,
    const float* __restrict__ b0, const float* __restrict__ r0,
    const float* __restrict__ bias0,
    unsigned short* __restrict__ wTm0, float* __restrict__ biasM0)
{
    __shared__ float sw[128];
    __shared__ float spb[128];
    __shared__ float red[2];
    int n = blockIdx.x, d = threadIdx.x;
    float acc = 0.f, accb = 0.f;
    for (int ch = 0; ch < 6; ++ch) {
        int j0 = ch * 128;
        __syncthreads();
        int j = j0 + d;
        float wv;
        if (n < 256)      wv = b0[(size_t)j * 256 + n];
        else if (n < 512) wv = b0[768 * 256 + (size_t)j * 256 + (n - 256)];
        else              wv = r0[(size_t)j * 256 + (n - 512)];
        sw[d] = wv;
        spb[d] = pb[j];
        __syncthreads();
#pragma unroll 8
        for (int jj = 0; jj < 128; ++jj)
            acc += PT[(size_t)(j0 + jj) * 128 + d] * sw[jj];
        accb += spb[d] * sw[d];
    }
    for (int o = 32; o > 0; o >>= 1) accb += __shfl_xor(accb, o);
    if ((d & 63) == 0) red[d >> 6] = accb;
    __syncthreads();
    if (d == 0)
        biasM0[n] = red[0] + red[1] + (n >= 512 ? bias0[n - 512] : 0.f);
    wTm0[(size_t)n * 128 + d] = f2bf(acc);
}

// l1/l2 weight transposes + biasM fills
__global__ __launch_bounds__(256) void prep_k(
    const float* __restrict__ b1, const float* __restrict__ r1, const float* __restrict__ bias1,
    const float* __restrict__ b2, const float* __restrict__ r2, const float* __restrict__ bias2,
    unsigned short* __restrict__ wTm1, unsigned short* __restrict__ wTm2,
    float* __restrict__ biasM1, float* __restrict__ biasM2)
{
    int b = blockIdx.x;
    if (b < 1536) {
        int layer = b / 768;
        int r = b % 768;
        int seg = r / 256;
        int k = r % 256;
        const float* bb = layer ? b2 : b1;
        const float* rr = layer ? r2 : r1;
        const float* in = (seg < 2) ? (bb + (size_t)seg * 256 * 256) : rr;
        unsigned short* out = layer ? wTm2 : wTm1;
        out[(size_t)(seg * 256 + threadIdx.x) * 256 + k] = f2bf(in[(size_t)k * 256 + threadIdx.x]);
    } else {
        int i = b - 1536;          // 0..5
        int layer = i / 3;
        int part = i % 3;
        int n = part * 256 + threadIdx.x;
        float* bm = layer ? biasM2 : biasM1;
        const float* bs = layer ? bias2 : bias1;
        bm[n] = (n >= 512) ? bs[n - 512] : 0.f;
    }
}

__global__ void bnfin_k(const float* __restrict__ bnsum, const float* __restrict__ gamma,
                        const float* __restrict__ beta, float* __restrict__ bnss)
{
    int c = threadIdx.x;
    float mu = bnsum[c] * (1.f / M_REAL);
    float var = bnsum[256 + c] * (1.f / M_REAL) - mu * mu;
    var = fmaxf(var, 0.f);
    float inv = rsqrtf(var + BN_EPS);
    float sc = gamma[c] * inv;
    bnss[c] = sc;
    bnss[256 + c] = beta[c] - mu * sc;
}

template<bool LAST>
__global__ __launch_bounds__(256) void apply_k(const float* __restrict__ y,
                                               const float* __restrict__ bnss,
                                               unsigned short* __restrict__ xn,
                                               float* __restrict__ outp)
{
    int i = blockIdx.x * 256 + threadIdx.x;
    int row = i >> 6;
    int c4 = (i & 63) * 4;
    f4 v = *(const f4*)(y + (size_t)row * 256 + c4);
    f4 sc = *(const f4*)(bnss + c4);
    f4 sh = *(const f4*)(bnss + 256 + c4);
    f4 r;
    r.x = fmaxf(v.x * sc.x + sh.x, 0.f);
    r.y = fmaxf(v.y * sc.y + sh.y, 0.f);
    r.z = fmaxf(v.z * sc.z + sh.z, 0.f);
    r.w = fmaxf(v.w * sc.w + sh.w, 0.f);
    if (LAST) {
        *(f4*)(outp + (size_t)row * 256 + c4) = r;
    } else {
        ushort4 u;
        u.x = f2bf(r.x); u.y = f2bf(r.y); u.z = f2bf(r.z); u.w = f2bf(r.w);
        *(ushort4*)(xn + (size_t)row * 256 + c4) = u;
    }
}

extern "C" void kernel_launch(void* const* d_in, const int* in_sizes, int n_in,
                              void* d_out, int out_size, void* d_ws, size_t ws_size,
                              hipStream_t stream)
{
    const int*   edge_index = (const int*)d_in[0];
    const int*   edge_type  = (const int*)d_in[1];
    const float* emb    = (const float*)d_in[2];
    const float* proj_w = (const float*)d_in[3];
    const float* proj_b = (const float*)d_in[4];
    const float* comp[3]  = {(const float*)d_in[5],  (const float*)d_in[11], (const float*)d_in[17]};
    const float* bases[3] = {(const float*)d_in[6],  (const float*)d_in[12], (const float*)d_in[18]};
    const float* root[3]  = {(const float*)d_in[7],  (const float*)d_in[13], (const float*)d_in[19]};
    const float* biasp[3] = {(const float*)d_in[8],  (const float*)d_in[14], (const float*)d_in[20]};
    const float* gamma[3] = {(const float*)d_in[9],  (const float*)d_in[15], (const float*)d_in[21]};
    const float* beta[3]  = {(const float*)d_in[10], (const float*)d_in[16], (const float*)d_in[22]};

    char* ws = (char*)d_ws;
    size_t off = 0;
    auto alloc = [&](size_t bytes) -> char* {
        char* p = ws + off;
        off = (off + bytes + 255) & ~(size_t)255;
        return p;
    };

    float*          y    = (float*)alloc((size_t)NNODES * 256 * 4);   // x0 aliased at start
    unsigned short* x1   = (unsigned short*)alloc((size_t)NNODES * 256 * 2);
    unsigned short* x2   = (unsigned short*)alloc((size_t)NNODES * 256 * 2);
    unsigned short* h    = (unsigned short*)alloc((size_t)NNODES * 512 * 2);
    float*          yroot= (float*)alloc((size_t)NNODES * 256 * 4);
    unsigned int*   cnt  = (unsigned int*)alloc((size_t)NNODES * NREL * 4);
    unsigned int*   cntd = (unsigned int*)alloc((size_t)NNODES * 4);
    unsigned int*   rowptr = (unsigned int*)alloc((size_t)(NNODES + 1) * 4);
    unsigned int*   cursor = (unsigned int*)alloc((size_t)NNODES * 4);
    unsigned int*   partial = (unsigned int*)alloc((size_t)NNODES * 4);
    unsigned int*   bsum = (unsigned int*)alloc(128 * 4);
    float2*         erec = (float2*)alloc((size_t)NEDGE * 8);
    float*          PT   = (float*)alloc((size_t)768 * 128 * 4);
    unsigned short* wTm0 = (unsigned short*)alloc((size_t)768 * 128 * 2);
    unsigned short* wTm1 = (unsigned short*)alloc((size_t)768 * 256 * 2);
    unsigned short* wTm2 = (unsigned short*)alloc((size_t)768 * 256 * 2);
    float* biasM = (float*)alloc(3 * 768 * 4);
    float* bns   = (float*)alloc(3 * 512 * 4);
    float* bnss  = (float*)alloc(3 * 512 * 4);

    unsigned short* x0 = (unsigned short*)y;   // x0 dead before y first written

    zero_k<<<3125, 256, 0, stream>>>(cnt, cntd, cursor, bns);
    norm_k<<<NNODES / 4, 256, 0, stream>>>(emb, x0);
    cnt_k<<<(NEDGE + 255) / 256, 256, 0, stream>>>(edge_index, edge_type, cnt, cntd);
    scan1_k<<<SCAN_NB, SCAN_B, 0, stream>>>(cntd, partial, bsum);
    scan2_k<<<1, 128, 0, stream>>>(bsum);
    scan3_k<<<SCAN_NB, SCAN_B, 0, stream>>>(partial, bsum, rowptr);
    fill_k<<<(NEDGE + 255) / 256, 256, 0, stream>>>(edge_index, edge_type, cnt, rowptr,
                                                    cursor, erec);

    pt_k<<<768, 128, 0, stream>>>(proj_w, PT);
    pm_k<<<768, 128, 0, stream>>>(PT, proj_b, bases[0], root[0], biasp[0], wTm0, biasM);
    prep_k<<<1542, 256, 0, stream>>>(bases[1], root[1], biasp[1],
                                     bases[2], root[2], biasp[2],
                                     wTm1, wTm2, biasM + 768, biasM + 2 * 768);

    // ---- layer 0 (A = x0, K = 128 after P-folding) ----
    gemm2_k<128><<<MT64, 256, 0, stream>>>(x0, wTm0, biasM, h, yroot);
    gather3_k<<<NNODES / 4, 256, 0, stream>>>(h, comp[0], rowptr, erec, yroot, y);
    bnsum_k<<<500, 256, 0, stream>>>(y, bns);
    bnfin_k<<<1, 256, 0, stream>>>(bns, gamma[0], beta[0], bnss);
    apply_k<false><<<(NNODES * 64) / 256, 256, 0, stream>>>(y, bnss, x1, nullptr);

    // ---- layer 1 (K = 256) ----
    gemm2_k<256><<<MT64, 256, 0, stream>>>(x1, wTm1, biasM + 768, h, yroot);
    gather3_k<<<NNODES / 4, 256, 0, stream>>>(h, comp[1], rowptr, erec, yroot, y);
    bnsum_k<<<500, 256, 0, stream>>>(y, bns + 512);
    bnfin_k<<<1, 256, 0, stream>>>(bns + 512, gamma[1], beta[1], bnss + 512);
    apply_k<false><<<(NNODES * 64) / 256, 256, 0, stream>>>(y, bnss + 512, x2, nullptr);

    // ---- layer 2 (K = 256) ----
    gemm2_k<256><<<MT64, 256, 0, stream>>>(x2, wTm2, biasM + 2 * 768, h, yroot);
    gather3_k<<<NNODES / 4, 256, 0, stream>>>(h, comp[2], rowptr, erec, yroot, y);
    bnsum_k<<<500, 256, 0, stream>>>(y, bns + 1024);
    bnfin_k<<<1, 256, 0, stream>>>(bns + 1024, gamma[2], beta[2], bnss + 1024);
    apply_k<true><<<(NNODES * 64) / 256, 256, 0, stream>>>(y, bnss + 1024, nullptr, (float*)d_out);
}

// Round 8
// 535.269 us; speedup vs baseline: 2.6907x; 1.2957x over previous
//
#include <hip/hip_runtime.h>
#include <hip/hip_bf16.h>

#define NNODES 50000
#define NREL   16
#define NEDGE  400000
#define BN_EPS 1e-5f
#define M_REAL NNODES
#define M_TILES 391            /* ceil(50000/128) */
#define RPX    49              /* ceil(391/8) row-blocks per XCD */
#define SCAN_B 512
#define SCAN_NB ((NNODES + SCAN_B - 1) / SCAN_B)   /* 98 */

typedef __attribute__((ext_vector_type(8))) short short8;
typedef __attribute__((ext_vector_type(4))) float f4;

__device__ __forceinline__ float bf2f(unsigned short u) {
    union { unsigned int i; float f; } x; x.i = ((unsigned int)u) << 16; return x.f;
}
__device__ __forceinline__ unsigned short f2bf(float f) {
    __hip_bfloat16 h = __float2bfloat16(f);
    union { __hip_bfloat16 h; unsigned short u; } x; x.h = h; return x.u;
}

__device__ __forceinline__ void g2l16(const unsigned short* g, unsigned short* l) {
    __builtin_amdgcn_global_load_lds(
        (const __attribute__((address_space(1))) unsigned int*)g,
        (__attribute__((address_space(3))) unsigned int*)l,
        16, 0, 0);
}

// ---------------------------------------------------------------------------
// GEMM (R4-verified m97 structure): y[M,256] = A[M,K] @ WT[256,K]^T + bias
// + BN sums (s1,s2 per column -> atomics). 128x128 tile, BK=64,
// global_load_lds staging w/ chunk swizzle, XCD-aware block swizzle.
// A row layout = [u0 | u1 | x | (t-chunk)]  matching WT's K-rows.
// ---------------------------------------------------------------------------
template<int K>
__global__ __launch_bounds__(256) void gemm3_k(
    const unsigned short* __restrict__ A,
    const unsigned short* __restrict__ WT,
    const float* __restrict__ bias,
    float* __restrict__ y,
    float* __restrict__ bns)
{
    const int lin = blockIdx.x;
    const int xcd = lin & 7;
    const int idx = lin >> 3;
    const int row_blk = xcd * RPX + (idx >> 1);
    const int nt = idx & 1;
    if (row_blk >= M_TILES) return;
    const int tile_m = row_blk * 128;
    const int tile_n = nt * 128;

    __shared__ unsigned short As[128 * 64];
    __shared__ unsigned short Bs[128 * 64];

    const int w = threadIdx.x >> 6;
    const int l = threadIdx.x & 63;
    const int lm = l & 15;
    const int kq = l >> 4;
    const int wm = (w & 1) << 6;
    const int wn = (w >> 1) << 6;

    const int lrow = l >> 3;
    const int chunk = ((l & 7) + 8 - lrow) & 7;
    const unsigned short* srcA[4];
    const unsigned short* srcB[4];
    unsigned short* dstA[4];
    unsigned short* dstB[4];
#pragma unroll
    for (int it = 0; it < 4; ++it) {
        int rt = it * 32 + w * 8 + lrow;
        int rg = tile_m + rt; if (rg >= M_REAL) rg = M_REAL - 1;
        srcA[it] = A  + (size_t)rg * K + chunk * 8;
        srcB[it] = WT + (size_t)(tile_n + rt) * K + chunk * 8;
        dstA[it] = As + (it * 32 + w * 8) * 64;
        dstB[it] = Bs + (it * 32 + w * 8) * 64;
    }

    unsigned aoff[4], boff[4];
#pragma unroll
    for (int mi = 0; mi < 4; ++mi) {
        aoff[mi] = (unsigned)((wm + mi * 16 + lm) * 128 + (((kq + lm) & 7) << 4));
        boff[mi] = (unsigned)((wn + mi * 16 + lm) * 128 + (((kq + lm) & 7) << 4));
    }

    f4 acc[4][4];
#pragma unroll
    for (int mi = 0; mi < 4; ++mi)
#pragma unroll
        for (int ni = 0; ni < 4; ++ni) acc[mi][ni] = (f4){0.f, 0.f, 0.f, 0.f};

    for (int kc = 0; kc < K; kc += 64) {
#pragma unroll
        for (int it = 0; it < 4; ++it) {
            g2l16(srcA[it] + kc, dstA[it]);
            g2l16(srcB[it] + kc, dstB[it]);
        }
        __syncthreads();
#pragma unroll
        for (int kh = 0; kh < 2; ++kh) {
            const unsigned x = kh << 6;
            short8 af[4], bfr[4];
#pragma unroll
            for (int mi = 0; mi < 4; ++mi)
                af[mi] = *(const short8*)((const char*)As + (aoff[mi] ^ x));
#pragma unroll
            for (int ni = 0; ni < 4; ++ni)
                bfr[ni] = *(const short8*)((const char*)Bs + (boff[ni] ^ x));
#pragma unroll
            for (int mi = 0; mi < 4; ++mi)
#pragma unroll
                for (int ni = 0; ni < 4; ++ni)
                    acc[mi][ni] = __builtin_amdgcn_mfma_f32_16x16x32_bf16(
                        af[mi], bfr[ni], acc[mi][ni], 0, 0, 0);
        }
        __syncthreads();
    }

    int cols[4]; float bv[4];
#pragma unroll
    for (int ni = 0; ni < 4; ++ni) {
        cols[ni] = tile_n + wn + ni * 16 + lm;
        bv[ni] = bias[cols[ni]];
    }
    float s1[4] = {0.f, 0.f, 0.f, 0.f}, s2[4] = {0.f, 0.f, 0.f, 0.f};
#pragma unroll
    for (int mi = 0; mi < 4; ++mi) {
#pragma unroll
        for (int rg = 0; rg < 4; ++rg) {
            int row = tile_m + wm + mi * 16 + kq * 4 + rg;
            if (row < M_REAL) {
                size_t base = (size_t)row * 256;
#pragma unroll
                for (int ni = 0; ni < 4; ++ni) {
                    float v = acc[mi][ni][rg] + bv[ni];
                    y[base + cols[ni]] = v;
                    s1[ni] += v; s2[ni] += v * v;
                }
            }
        }
    }
#pragma unroll
    for (int ni = 0; ni < 4; ++ni) {
        float a = s1[ni], b = s2[ni];
        a += __shfl_xor(a, 16); a += __shfl_xor(a, 32);
        b += __shfl_xor(b, 16); b += __shfl_xor(b, 32);
        if (l < 16) {
            atomicAdd(&bns[cols[ni]], a);
            atomicAdd(&bns[256 + cols[ni]], b);
        }
    }
}

// ---------------------------------------------------------------------------
// gather in INPUT space: one wave per dst node; 4-edge unroll.
// buf row (stride S=3D(+64)): [u0 0..D | u1 D..2D | x 2D..3D | t-chunk (l0)]
// u_b[dst] = sum_e (c_b/d) * x_src ; t_b = sum_e c_b/d (layer 0 only)
// ---------------------------------------------------------------------------
template<int D, bool HAST>
__global__ __launch_bounds__(256) void gatheru_k(
    unsigned short* buf, const float* __restrict__ comp,
    const unsigned int* __restrict__ rowptr, const float2* __restrict__ erec)
{
    constexpr int E = D / 64;                 // bf16 elems per lane (2 or 4)
    constexpr int S = 3 * D + (HAST ? 64 : 0);
    __shared__ float scomp[32];
    if (threadIdx.x < 32) scomp[threadIdx.x] = comp[threadIdx.x];
    __syncthreads();
    int node = blockIdx.x * 4 + (threadIdx.x >> 6);
    int lane = threadIdx.x & 63;
    unsigned int p0 = rowptr[node], p1 = rowptr[node + 1];
    const unsigned short* xbase = buf + 2 * D + lane * E;

    float a0[E], a1[E], b0[E], b1[E];
#pragma unroll
    for (int e = 0; e < E; ++e) { a0[e] = a1[e] = b0[e] = b1[e] = 0.f; }
    float t0 = 0.f, t1 = 0.f;

    unsigned int p = p0;
    for (; p + 4 <= p1; p += 4) {
        float2 r[4];
        unsigned short v[4][E];
#pragma unroll
        for (int j = 0; j < 4; ++j) r[j] = erec[p + j];
#pragma unroll
        for (int j = 0; j < 4; ++j) {
            unsigned q = __float_as_uint(r[j].x);
            const unsigned short* s = xbase + (size_t)(q >> 4) * S;
            if (E == 2) { ushort2 t = *(const ushort2*)s; v[j][0] = t.x; v[j][1] = t.y; }
            else        { ushort4 t = *(const ushort4*)s; v[j][0] = t.x; v[j][1] = t.y;
                          v[j][2] = t.z; v[j][3] = t.w; }
        }
#pragma unroll
        for (int j = 0; j < 4; ++j) {
            unsigned q = __float_as_uint(r[j].x);
            float w0 = scomp[(q & 15) * 2] * r[j].y;
            float w1 = scomp[(q & 15) * 2 + 1] * r[j].y;
            if (HAST) { t0 += w0; t1 += w1; }
            float* d0 = (j & 1) ? b0 : a0;
            float* d1 = (j & 1) ? b1 : a1;
#pragma unroll
            for (int e = 0; e < E; ++e) {
                float xv = bf2f(v[j][e]);
                d0[e] += w0 * xv;
                d1[e] += w1 * xv;
            }
        }
    }
    for (; p < p1; ++p) {
        float2 r = erec[p];
        unsigned q = __float_as_uint(r.x);
        const unsigned short* s = xbase + (size_t)(q >> 4) * S;
        unsigned short v[E];
        if (E == 2) { ushort2 t = *(const ushort2*)s; v[0] = t.x; v[1] = t.y; }
        else        { ushort4 t = *(const ushort4*)s; v[0] = t.x; v[1] = t.y;
                      v[2] = t.z; v[3] = t.w; }
        float w0 = scomp[(q & 15) * 2] * r.y;
        float w1 = scomp[(q & 15) * 2 + 1] * r.y;
        if (HAST) { t0 += w0; t1 += w1; }
#pragma unroll
        for (int e = 0; e < E; ++e) {
            float xv = bf2f(v[e]);
            a0[e] += w0 * xv;
            a1[e] += w1 * xv;
        }
    }

    unsigned short* orow = buf + (size_t)node * S;
    if (E == 2) {
        ushort2 o0, o1;
        o0.x = f2bf(a0[0] + b0[0]); o0.y = f2bf(a0[1] + b0[1]);
        o1.x = f2bf(a1[0] + b1[0]); o1.y = f2bf(a1[1] + b1[1]);
        *(ushort2*)(orow + lane * 2) = o0;
        *(ushort2*)(orow + D + lane * 2) = o1;
    } else {
        ushort4 o0, o1;
        o0.x = f2bf(a0[0] + b0[0]); o0.y = f2bf(a0[1] + b0[1]);
        o0.z = f2bf(a0[2] + b0[2]); o0.w = f2bf(a0[3] + b0[3]);
        o1.x = f2bf(a1[0] + b1[0]); o1.y = f2bf(a1[1] + b1[1]);
        o1.z = f2bf(a1[2] + b1[2]); o1.w = f2bf(a1[3] + b1[3]);
        *(ushort4*)(orow + lane * 4) = o0;
        *(ushort4*)(orow + D + lane * 4) = o1;
    }
    if (HAST) {
        unsigned short tv = (lane == 0) ? f2bf(t0) : (lane == 1) ? f2bf(t1) : (unsigned short)0;
        orow[3 * D + lane] = tv;
    }
}

// row L2-normalize emb -> bf16 x0, into axl0 at col offset 256 (stride 448)
__global__ __launch_bounds__(256) void norm_k(const float* __restrict__ emb,
                                              unsigned short* __restrict__ buf)
{
    int node = blockIdx.x * 4 + (threadIdx.x >> 6);
    int lane = threadIdx.x & 63;
    const float2* p = (const float2*)(emb + (size_t)node * 128);
    float2 v = p[lane];
    float ss = v.x * v.x + v.y * v.y;
#pragma unroll
    for (int o = 32; o > 0; o >>= 1) ss += __shfl_xor(ss, o);
    float inv = 1.f / fmaxf(sqrtf(ss), 1e-12f);
    unsigned short* row = buf + (size_t)node * 448 + 256;
    unsigned int pack = (unsigned int)f2bf(v.x * inv) | ((unsigned int)f2bf(v.y * inv) << 16);
    ((unsigned int*)row)[lane] = pack;
}

// zero cnt(800000) cntd(50000) cursor(50000) bns(1536)
__global__ void zero_k(unsigned int* __restrict__ cnt, unsigned int* __restrict__ cntd,
                       unsigned int* __restrict__ cursor, float* __restrict__ bns)
{
    int i = blockIdx.x * 256 + threadIdx.x;
    if (i < 800000) cnt[i] = 0u;
    if (i < 50000) { cntd[i] = 0u; cursor[i] = 0u; }
    if (i < 1536) bns[i] = 0.f;
}

__global__ void cnt_k(const int* __restrict__ ei, const int* __restrict__ et,
                      unsigned int* __restrict__ cnt, unsigned int* __restrict__ cntd)
{
    int e = blockIdx.x * 256 + threadIdx.x;
    if (e >= NEDGE) return;
    int dst = ei[NEDGE + e];
    atomicAdd(&cnt[(size_t)dst * NREL + et[e]], 1u);
    atomicAdd(&cntd[dst], 1u);
}

__global__ __launch_bounds__(SCAN_B) void scan1_k(const unsigned int* __restrict__ cntd,
                                                  unsigned int* __restrict__ partial,
                                                  unsigned int* __restrict__ bsum)
{
    __shared__ unsigned int s[SCAN_B];
    int i = blockIdx.x * SCAN_B + threadIdx.x;
    unsigned int v = (i < NNODES) ? cntd[i] : 0u;
    s[threadIdx.x] = v;
    __syncthreads();
    for (int off = 1; off < SCAN_B; off <<= 1) {
        unsigned int t = (threadIdx.x >= off) ? s[threadIdx.x - off] : 0u;
        __syncthreads();
        s[threadIdx.x] += t;
        __syncthreads();
    }
    if (i < NNODES) partial[i] = s[threadIdx.x];
    if (threadIdx.x == SCAN_B - 1) bsum[blockIdx.x] = s[SCAN_B - 1];
}

__global__ __launch_bounds__(128) void scan2_k(unsigned int* __restrict__ bsum)
{
    __shared__ unsigned int s[128];
    unsigned int v = (threadIdx.x < SCAN_NB) ? bsum[threadIdx.x] : 0u;
    s[threadIdx.x] = v;
    __syncthreads();
    for (int off = 1; off < 128; off <<= 1) {
        unsigned int t = (threadIdx.x >= off) ? s[threadIdx.x - off] : 0u;
        __syncthreads();
        s[threadIdx.x] += t;
        __syncthreads();
    }
    if (threadIdx.x < SCAN_NB) bsum[threadIdx.x] = s[threadIdx.x];
}

__global__ __launch_bounds__(SCAN_B) void scan3_k(const unsigned int* __restrict__ partial,
                                                  const unsigned int* __restrict__ bsum,
                                                  unsigned int* __restrict__ rowptr)
{
    int i = blockIdx.x * SCAN_B + threadIdx.x;
    if (i >= NNODES) return;
    unsigned int off = (blockIdx.x > 0) ? bsum[blockIdx.x - 1] : 0u;
    rowptr[i + 1] = partial[i] + off;
    if (i == 0) rowptr[0] = 0u;
}

__global__ void fill_k(const int* __restrict__ ei, const int* __restrict__ et,
                       const unsigned int* __restrict__ cnt,
                       const unsigned int* __restrict__ rowptr,
                       unsigned int* __restrict__ cursor,
                       float2* __restrict__ erec)
{
    int e = blockIdx.x * 256 + threadIdx.x;
    if (e >= NEDGE) return;
    int dst = ei[NEDGE + e];
    int t = et[e];
    unsigned int c = cnt[(size_t)dst * NREL + t];
    unsigned int pos = rowptr[dst] + atomicAdd(&cursor[dst], 1u);
    float2 r;
    r.x = __uint_as_float(((unsigned)ei[e] << 4) | (unsigned)t);
    r.y = 1.f / (float)(c ? c : 1u);
    erec[pos] = r;
}

// PT[j*128+d] = proj_w[d*768+j]
__global__ __launch_bounds__(128) void pt_k(const float* __restrict__ proj_w,
                                            float* __restrict__ PT)
{
    int j = blockIdx.x, d = threadIdx.x;
    PT[(size_t)j * 128 + d] = proj_w[(size_t)d * 768 + j];
}

// layer-0 folded weights: wTm0[n][448]: [P@B0 | P@B1 | P@R | pb@B0, pb@B1, 0..]
// grid 768 = seg(3) x n(256); 128 threads (d)
__global__ __launch_bounds__(128) void pm_k(
    const float* __restrict__ PT, const float* __restrict__ pb,
    const float* __restrict__ b0, const float* __restrict__ r0,
    const float* __restrict__ bias0,
    unsigned short* __restrict__ wTm0, float* __restrict__ biasM0)
{
    __shared__ float sw[128];
    __shared__ float spb[128];
    __shared__ float red[2];
    int seg = blockIdx.x >> 8;
    int n = blockIdx.x & 255;
    int d = threadIdx.x;
    float acc = 0.f, accb = 0.f;
    for (int ch = 0; ch < 6; ++ch) {
        int j0 = ch * 128;
        __syncthreads();
        int j = j0 + d;
        float wv;
        if (seg == 0)      wv = b0[(size_t)j * 256 + n];
        else if (seg == 1) wv = b0[768 * 256 + (size_t)j * 256 + n];
        else               wv = r0[(size_t)j * 256 + n];
        sw[d] = wv;
        spb[d] = pb[j];
        __syncthreads();
#pragma unroll 8
        for (int jj = 0; jj < 128; ++jj)
            acc += PT[(size_t)(j0 + jj) * 128 + d] * sw[jj];
        accb += spb[d] * sw[d];
    }
    for (int o = 32; o > 0; o >>= 1) accb += __shfl_xor(accb, o);
    if ((d & 63) == 0) red[d >> 6] = accb;
    __syncthreads();
    float tb = red[0] + red[1];
    wTm0[(size_t)n * 448 + seg * 128 + d] = f2bf(acc);
    if (seg == 0) { if (d == 0) wTm0[(size_t)n * 448 + 384] = f2bf(tb); }
    else if (seg == 1) { if (d == 0) wTm0[(size_t)n * 448 + 385] = f2bf(tb); }
    else {
        if (d == 0) biasM0[n] = tb + bias0[n];
        if (d >= 2 && d < 64) wTm0[(size_t)n * 448 + 384 + d] = 0;
    }
}

// layers 1/2: wTm[n][768] = [B0 | B1 | R] rows; + biasM fills
__global__ __launch_bounds__(256) void prep_k(
    const float* __restrict__ b1, const float* __restrict__ r1, const float* __restrict__ bias1,
    const float* __restrict__ b2, const float* __restrict__ r2, const float* __restrict__ bias2,
    unsigned short* __restrict__ wTm1, unsigned short* __restrict__ wTm2,
    float* __restrict__ biasM1, float* __restrict__ biasM2)
{
    int b = blockIdx.x;
    int n = threadIdx.x;
    if (b < 1536) {
        int layer = b / 768;
        int rem = b % 768;
        int seg = rem / 256;
        int k = rem % 256;
        const float* bb = layer ? b2 : b1;
        const float* rr = layer ? r2 : r1;
        const float* in = (seg < 2) ? (bb + (size_t)seg * 256 * 256) : rr;
        unsigned short* out = layer ? wTm2 : wTm1;
        out[(size_t)n * 768 + seg * 256 + k] = f2bf(in[(size_t)k * 256 + n]);
    } else {
        int layer = b - 1536;
        float* bm = layer ? biasM2 : biasM1;
        const float* bs = layer ? bias2 : bias1;
        bm[n] = bs[n];
    }
}

__global__ void bnfin_k(const float* __restrict__ bnsum, const float* __restrict__ gamma,
                        const float* __restrict__ beta, float* __restrict__ bnss)
{
    int c = threadIdx.x;
    float mu = bnsum[c] * (1.f / M_REAL);
    float var = bnsum[256 + c] * (1.f / M_REAL) - mu * mu;
    var = fmaxf(var, 0.f);
    float inv = rsqrtf(var + BN_EPS);
    float sc = gamma[c] * inv;
    bnss[c] = sc;
    bnss[256 + c] = beta[c] - mu * sc;
}

// y -> BN+relu -> bf16 x into next layer's buf (stride 768, offset 512), or f32 d_out
template<bool LAST>
__global__ __launch_bounds__(256) void apply_k(const float* __restrict__ y,
                                               const float* __restrict__ bnss,
                                               unsigned short* __restrict__ xn,
                                               float* __restrict__ outp)
{
    int i = blockIdx.x * 256 + threadIdx.x;
    int row = i >> 6;
    int c4 = (i & 63) * 4;
    f4 v = *(const f4*)(y + (size_t)row * 256 + c4);
    f4 sc = *(const f4*)(bnss + c4);
    f4 sh = *(const f4*)(bnss + 256 + c4);
    f4 r;
    r.x = fmaxf(v.x * sc.x + sh.x, 0.f);
    r.y = fmaxf(v.y * sc.y + sh.y, 0.f);
    r.z = fmaxf(v.z * sc.z + sh.z, 0.f);
    r.w = fmaxf(v.w * sc.w + sh.w, 0.f);
    if (LAST) {
        *(f4*)(outp + (size_t)row * 256 + c4) = r;
    } else {
        ushort4 u;
        u.x = f2bf(r.x); u.y = f2bf(r.y); u.z = f2bf(r.z); u.w = f2bf(r.w);
        *(ushort4*)(xn + (size_t)row * 768 + 512 + c4) = u;
    }
}

extern "C" void kernel_launch(void* const* d_in, const int* in_sizes, int n_in,
                              void* d_out, int out_size, void* d_ws, size_t ws_size,
                              hipStream_t stream)
{
    const int*   edge_index = (const int*)d_in[0];
    const int*   edge_type  = (const int*)d_in[1];
    const float* emb    = (const float*)d_in[2];
    const float* proj_w = (const float*)d_in[3];
    const float* proj_b = (const float*)d_in[4];
    const float* comp[3]  = {(const float*)d_in[5],  (const float*)d_in[11], (const float*)d_in[17]};
    const float* bases[3] = {(const float*)d_in[6],  (const float*)d_in[12], (const float*)d_in[18]};
    const float* root[3]  = {(const float*)d_in[7],  (const float*)d_in[13], (const float*)d_in[19]};
    const float* biasp[3] = {(const float*)d_in[8],  (const float*)d_in[14], (const float*)d_in[20]};
    const float* gamma[3] = {(const float*)d_in[9],  (const float*)d_in[15], (const float*)d_in[21]};
    const float* beta[3]  = {(const float*)d_in[10], (const float*)d_in[16], (const float*)d_in[22]};

    char* ws = (char*)d_ws;
    size_t off = 0;
    auto alloc = [&](size_t bytes) -> char* {
        char* p = ws + off;
        off = (off + bytes + 255) & ~(size_t)255;
        return p;
    };

    unsigned short* axl0 = (unsigned short*)alloc((size_t)NNODES * 448 * 2);
    unsigned short* axl1 = (unsigned short*)alloc((size_t)NNODES * 768 * 2);
    unsigned short* axl2 = (unsigned short*)alloc((size_t)NNODES * 768 * 2);
    float*          y    = (float*)alloc((size_t)NNODES * 256 * 4);
    unsigned int*   cnt  = (unsigned int*)alloc((size_t)NNODES * NREL * 4);
    unsigned int*   cntd = (unsigned int*)alloc((size_t)NNODES * 4);
    unsigned int*   rowptr = (unsigned int*)alloc((size_t)(NNODES + 1) * 4);
    unsigned int*   cursor = (unsigned int*)alloc((size_t)NNODES * 4);
    unsigned int*   partial = (unsigned int*)alloc((size_t)NNODES * 4);
    unsigned int*   bsum = (unsigned int*)alloc(128 * 4);
    float2*         erec = (float2*)alloc((size_t)NEDGE * 8);
    float*          PT   = (float*)alloc((size_t)768 * 128 * 4);
    unsigned short* wTm0 = (unsigned short*)alloc((size_t)256 * 448 * 2);
    unsigned short* wTm1 = (unsigned short*)alloc((size_t)256 * 768 * 2);
    unsigned short* wTm2 = (unsigned short*)alloc((size_t)256 * 768 * 2);
    float* biasM = (float*)alloc(3 * 256 * 4);
    float* bns   = (float*)alloc(3 * 512 * 4);
    float* bnss  = (float*)alloc(3 * 512 * 4);

    zero_k<<<3125, 256, 0, stream>>>(cnt, cntd, cursor, bns);
    norm_k<<<NNODES / 4, 256, 0, stream>>>(emb, axl0);
    cnt_k<<<(NEDGE + 255) / 256, 256, 0, stream>>>(edge_index, edge_type, cnt, cntd);
    scan1_k<<<SCAN_NB, SCAN_B, 0, stream>>>(cntd, partial, bsum);
    scan2_k<<<1, 128, 0, stream>>>(bsum);
    scan3_k<<<SCAN_NB, SCAN_B, 0, stream>>>(partial, bsum, rowptr);
    fill_k<<<(NEDGE + 255) / 256, 256, 0, stream>>>(edge_index, edge_type, cnt, rowptr,
                                                    cursor, erec);

    pt_k<<<768, 128, 0, stream>>>(proj_w, PT);
    pm_k<<<768, 128, 0, stream>>>(PT, proj_b, bases[0], root[0], biasp[0], wTm0, biasM);
    prep_k<<<1538, 256, 0, stream>>>(bases[1], root[1], biasp[1],
                                     bases[2], root[2], biasp[2],
                                     wTm1, wTm2, biasM + 256, biasM + 512);

    // ---- layer 0 (D=128, K=448 with t-chunk) ----
    gatheru_k<128, true><<<NNODES / 4, 256, 0, stream>>>(axl0, comp[0], rowptr, erec);
    gemm3_k<448><<<8 * RPX * 2, 256, 0, stream>>>(axl0, wTm0, biasM, y, bns);
    bnfin_k<<<1, 256, 0, stream>>>(bns, gamma[0], beta[0], bnss);
    apply_k<false><<<(NNODES * 64) / 256, 256, 0, stream>>>(y, bnss, axl1, nullptr);

    // ---- layer 1 (D=256, K=768) ----
    gatheru_k<256, false><<<NNODES / 4, 256, 0, stream>>>(axl1, comp[1], rowptr, erec);
    gemm3_k<768><<<8 * RPX * 2, 256, 0, stream>>>(axl1, wTm1, biasM + 256, y, bns + 512);
    bnfin_k<<<1, 256, 0, stream>>>(bns + 512, gamma[1], beta[1], bnss + 512);
    apply_k<false><<<(NNODES * 64) / 256, 256, 0, stream>>>(y, bnss + 512, axl2, nullptr);

    // ---- layer 2 (D=256, K=768) ----
    gatheru_k<256, false><<<NNODES / 4, 256, 0, stream>>>(axl2, comp[2], rowptr, erec);
    gemm3_k<768><<<8 * RPX * 2, 256, 0, stream>>>(axl2, wTm2, biasM + 512, y, bns + 1024);
    bnfin_k<<<1, 256, 0, stream>>>(bns + 1024, gamma[2], beta[2], bnss + 1024);
    apply_k<true><<<(NNODES * 64) / 256, 256, 0, stream>>>(y, bnss + 1024, nullptr, (float*)d_out);
}